// Round 7
// baseline (240.296 us; speedup 1.0000x reference)
//
#include <hip/hip_runtime.h>

typedef __attribute__((ext_vector_type(8))) short short8;
typedef __attribute__((ext_vector_type(4))) float f32x4;

#define ROWS 16384   // B*N
#define DIM 64
#define NCODES 8192
#define MARGIN 0.008f
#define KT_FB 256
#define CTS_PER_BLOCK 32   // 512 codes per y-block
#define CHUNK 4            // cts staged per LDS chunk (16 KB)

// ws layout (bytes)
#define WS_BEST   0            // 16384 * 8
#define WS_COUNTS 131072       // 8192 * 4
#define WS_ENH    163840       // 8192 * 4
#define WS_ESWZ   196608       // 8192*64*2 terms * 2B = 2097152
#define WS_NEED   2293760

__device__ __forceinline__ unsigned long long pack_score(float s, int idx) {
  unsigned u = __float_as_uint(s);
  u ^= (unsigned)((int)u >> 31) | 0x80000000u;
  return ((unsigned long long)u << 32) | (unsigned)(0xFFFF - idx);
}
__device__ __forceinline__ unsigned short bf16hi(float f) {
  unsigned u = __float_as_uint(f);
  return (unsigned short)((u + 0x7FFFu + ((u >> 16) & 1u)) >> 16);
}

__global__ void vq_enorm(const float* __restrict__ embed, float* __restrict__ enh) {
  int k = blockIdx.x * 256 + threadIdx.x;
  const float4* e4 = (const float4*)(embed + (size_t)k * DIM);
  float a = 0.f, b = 0.f, c = 0.f, d = 0.f;
#pragma unroll
  for (int i = 0; i < DIM / 4; ++i) {
    float4 v = e4[i];
    a = fmaf(v.x, v.x, a); b = fmaf(v.y, v.y, b);
    c = fmaf(v.z, v.z, c); d = fmaf(v.w, v.w, d);
  }
  enh[k] = 0.5f * ((a + b) + (c + d));
}

// Pre-swizzle embed into MFMA B-fragment order, split hi/lo bf16.
// frag index = ct*4 + kc*2 + term (term 0=hi, 1=lo); element l*16B within frag.
__global__ void vq_prep_e(const float* __restrict__ embed, short* __restrict__ eswz) {
  int u = blockIdx.x * 256 + threadIdx.x;  // 65536 = 512ct * 2kc * 64l
  int l = u & 63, kc = (u >> 6) & 1, ct = u >> 7;
  int code = ct * 16 + (l & 15);
  int kb = kc * 32 + (l >> 4) * 8;
  const float* er = embed + (size_t)code * DIM + kb;
  short8 h8, l8;
#pragma unroll
  for (int j = 0; j < 8; ++j) {
    float v = er[j];
    unsigned short h = bf16hi(v);
    float r = v - __uint_as_float((unsigned)h << 16);
    h8[j] = (short)h;
    l8[j] = (short)bf16hi(r);
  }
  short8* dst = (short8*)eswz;
  size_t frag = (size_t)ct * 4 + kc * 2;
  dst[(frag + 0) * 64 + l] = h8;
  dst[(frag + 1) * 64 + l] = l8;
}

// Screen: block = 4 waves x 32 rows, all waves share the same 512-code range.
// B-fragments staged into LDS in 4-ct chunks via global_load_lds; enh staged
// once per block. -||e||^2/2 folded into acc init (off the compare path).
// r6 lesson: latency wasn't the wall, residency was — request 8 waves/SIMD
// (VGPR fits at 64, LDS 18 KB -> 8 blocks/CU).
__global__ __launch_bounds__(256, 8) void vq_screen(
    const float* __restrict__ x, const float* __restrict__ embed,
    const short* __restrict__ eswz, const float* __restrict__ enh,
    unsigned long long* __restrict__ best) {
  const int t = threadIdx.x;
  const int l = t & 63, wid = t >> 6;
  const int cl = l & 15, grp = l >> 4;
  const int row0 = blockIdx.x * 128 + wid * 32;
  const int ct0 = blockIdx.y * CTS_PER_BLOCK;

  __shared__ short8 bstage[CHUNK * 4 * 64];  // 16 KB
  __shared__ float enh_s[CTS_PER_BLOCK * 16];  // 2 KB

  enh_s[t] = enh[ct0 * 16 + t];
  enh_s[256 + t] = enh[ct0 * 16 + 256 + t];

  // A fragments: x rows -> hi/lo bf16, built in-register (one-time).
  short8 ahi[2][2], alo[2][2];
#pragma unroll
  for (int s = 0; s < 2; ++s) {
    const float* xr = x + (size_t)(row0 + s * 16 + cl) * DIM;
#pragma unroll
    for (int kc = 0; kc < 2; ++kc) {
      const int kb = kc * 32 + grp * 8;
#pragma unroll
      for (int j = 0; j < 8; ++j) {
        float v = xr[kb + j];
        unsigned short h = bf16hi(v);
        float r = v - __uint_as_float((unsigned)h << 16);
        ahi[s][kc][j] = (short)h;
        alo[s][kc][j] = (short)bf16hi(r);
      }
    }
  }

  float bsc[2][4];
  int bidx[2][4];
#pragma unroll
  for (int s = 0; s < 2; ++s)
#pragma unroll
    for (int j = 0; j < 4; ++j) { bsc[s][j] = -3.4e38f; bidx[s][j] = 0; }

  for (int ch = 0; ch < CTS_PER_BLOCK / CHUNK; ++ch) {
    const int cc = ct0 + ch * CHUNK;
    // ---- stage chunk: 16 KB, 256 threads x 4 x 16 B, linear in lane ----
    {
      const char* gb = (const char*)eswz + (size_t)cc * 4 * 1024;
      char* lb = (char*)bstage;
#pragma unroll
      for (int i = 0; i < 4; ++i) {
        const int e = i * 256 + t;
        __builtin_amdgcn_global_load_lds(
            (const __attribute__((address_space(1))) void*)(gb + (size_t)e * 16),
            (__attribute__((address_space(3))) void*)(lb + e * 16), 16, 0, 0);
      }
    }
    __syncthreads();  // drains vmcnt -> LDS chunk (and enh_s on ch 0) visible

    // ---- compute 4 cts as 2 pairs, 4 independent acc chains per pair ----
#pragma unroll
    for (int p = 0; p < 2; ++p) {
      const int ctA = cc + 2 * p, ctB = ctA + 1;
      const int ciA = 2 * p, ciB = 2 * p + 1;
      float ehA = enh_s[(ctA - ct0) * 16 + cl];
      float ehB = enh_s[(ctB - ct0) * 16 + cl];
      short8 Ah0 = bstage[(ciA * 4 + 0) * 64 + l], Al0 = bstage[(ciA * 4 + 1) * 64 + l];
      short8 Ah1 = bstage[(ciA * 4 + 2) * 64 + l], Al1 = bstage[(ciA * 4 + 3) * 64 + l];
      short8 Bh0 = bstage[(ciB * 4 + 0) * 64 + l], Bl0 = bstage[(ciB * 4 + 1) * 64 + l];
      short8 Bh1 = bstage[(ciB * 4 + 2) * 64 + l], Bl1 = bstage[(ciB * 4 + 3) * 64 + l];

      f32x4 iA = {-ehA, -ehA, -ehA, -ehA};
      f32x4 iB = {-ehB, -ehB, -ehB, -ehB};
      f32x4 aA0 = iA, aA1 = iA, aB0 = iB, aB1 = iB;
      // k-chunk 0, term hi*hi
      aA0 = __builtin_amdgcn_mfma_f32_16x16x32_bf16(ahi[0][0], Ah0, aA0, 0, 0, 0);
      aA1 = __builtin_amdgcn_mfma_f32_16x16x32_bf16(ahi[1][0], Ah0, aA1, 0, 0, 0);
      aB0 = __builtin_amdgcn_mfma_f32_16x16x32_bf16(ahi[0][0], Bh0, aB0, 0, 0, 0);
      aB1 = __builtin_amdgcn_mfma_f32_16x16x32_bf16(ahi[1][0], Bh0, aB1, 0, 0, 0);
      // k-chunk 0, term lo*hi
      aA0 = __builtin_amdgcn_mfma_f32_16x16x32_bf16(alo[0][0], Ah0, aA0, 0, 0, 0);
      aA1 = __builtin_amdgcn_mfma_f32_16x16x32_bf16(alo[1][0], Ah0, aA1, 0, 0, 0);
      aB0 = __builtin_amdgcn_mfma_f32_16x16x32_bf16(alo[0][0], Bh0, aB0, 0, 0, 0);
      aB1 = __builtin_amdgcn_mfma_f32_16x16x32_bf16(alo[1][0], Bh0, aB1, 0, 0, 0);
      // k-chunk 0, term hi*lo
      aA0 = __builtin_amdgcn_mfma_f32_16x16x32_bf16(ahi[0][0], Al0, aA0, 0, 0, 0);
      aA1 = __builtin_amdgcn_mfma_f32_16x16x32_bf16(ahi[1][0], Al0, aA1, 0, 0, 0);
      aB0 = __builtin_amdgcn_mfma_f32_16x16x32_bf16(ahi[0][0], Bl0, aB0, 0, 0, 0);
      aB1 = __builtin_amdgcn_mfma_f32_16x16x32_bf16(ahi[1][0], Bl0, aB1, 0, 0, 0);
      // k-chunk 1, term hi*hi
      aA0 = __builtin_amdgcn_mfma_f32_16x16x32_bf16(ahi[0][1], Ah1, aA0, 0, 0, 0);
      aA1 = __builtin_amdgcn_mfma_f32_16x16x32_bf16(ahi[1][1], Ah1, aA1, 0, 0, 0);
      aB0 = __builtin_amdgcn_mfma_f32_16x16x32_bf16(ahi[0][1], Bh1, aB0, 0, 0, 0);
      aB1 = __builtin_amdgcn_mfma_f32_16x16x32_bf16(ahi[1][1], Bh1, aB1, 0, 0, 0);
      // k-chunk 1, term lo*hi
      aA0 = __builtin_amdgcn_mfma_f32_16x16x32_bf16(alo[0][1], Ah1, aA0, 0, 0, 0);
      aA1 = __builtin_amdgcn_mfma_f32_16x16x32_bf16(alo[1][1], Ah1, aA1, 0, 0, 0);
      aB0 = __builtin_amdgcn_mfma_f32_16x16x32_bf16(alo[0][1], Bh1, aB0, 0, 0, 0);
      aB1 = __builtin_amdgcn_mfma_f32_16x16x32_bf16(alo[1][1], Bh1, aB1, 0, 0, 0);
      // k-chunk 1, term hi*lo
      aA0 = __builtin_amdgcn_mfma_f32_16x16x32_bf16(ahi[0][1], Al1, aA0, 0, 0, 0);
      aA1 = __builtin_amdgcn_mfma_f32_16x16x32_bf16(ahi[1][1], Al1, aA1, 0, 0, 0);
      aB0 = __builtin_amdgcn_mfma_f32_16x16x32_bf16(ahi[0][1], Bl1, aB0, 0, 0, 0);
      aB1 = __builtin_amdgcn_mfma_f32_16x16x32_bf16(ahi[1][1], Bl1, aB1, 0, 0, 0);

      const int codeA = ctA * 16 + cl, codeB = ctB * 16 + cl;
#pragma unroll
      for (int j = 0; j < 4; ++j) {
        if (aA0[j] > bsc[0][j]) { bsc[0][j] = aA0[j]; bidx[0][j] = codeA; }
        if (aA1[j] > bsc[1][j]) { bsc[1][j] = aA1[j]; bidx[1][j] = codeA; }
        if (aB0[j] > bsc[0][j]) { bsc[0][j] = aB0[j]; bidx[0][j] = codeB; }
        if (aB1[j] > bsc[1][j]) { bsc[1][j] = aB1[j]; bidx[1][j] = codeB; }
      }
    }
    __syncthreads();  // protect LDS before next chunk's stage
  }

  // Row max over the 16 lanes (l&15) of each group; flag lane-bests within margin.
  unsigned fmask = 0;
#pragma unroll
  for (int s = 0; s < 2; ++s)
#pragma unroll
    for (int j = 0; j < 4; ++j) {
      float m = bsc[s][j];
      m = fmaxf(m, __shfl_xor(m, 1));
      m = fmaxf(m, __shfl_xor(m, 2));
      m = fmaxf(m, __shfl_xor(m, 4));
      m = fmaxf(m, __shfl_xor(m, 8));
      if (bsc[s][j] >= m - MARGIN) fmask |= 1u << (s * 4 + j);
    }

  // Exact fp32 rescore of flagged candidates (typically 1/lane), lane-compacted.
  float exact[2][4];
#pragma unroll
  for (int s = 0; s < 2; ++s)
#pragma unroll
    for (int j = 0; j < 4; ++j) exact[s][j] = -3.4e38f;

  while (__any((int)(fmask != 0))) {
    const bool act = fmask != 0;
    const int sel = __ffs(fmask) - 1;  // -1 if none (guarded by act)
    int code = 0;
#pragma unroll
    for (int s = 0; s < 2; ++s)
#pragma unroll
      for (int j = 0; j < 4; ++j)
        code = (sel == s * 4 + j) ? bidx[s][j] : code;
    int row = act ? (row0 + (sel >> 2) * 16 + grp * 4 + (sel & 3)) : row0;
    if (!act) code = 0;
    const float4* xr = (const float4*)(x + (size_t)row * DIM);
    const float4* er = (const float4*)(embed + (size_t)code * DIM);
    float a0 = 0, a1 = 0, a2 = 0, a3 = 0, n0 = 0, n1 = 0, n2 = 0, n3 = 0;
#pragma unroll
    for (int i = 0; i < 16; ++i) {
      float4 xv = xr[i], ev = er[i];
      a0 = fmaf(xv.x, ev.x, a0); a1 = fmaf(xv.y, ev.y, a1);
      a2 = fmaf(xv.z, ev.z, a2); a3 = fmaf(xv.w, ev.w, a3);
      n0 = fmaf(ev.x, ev.x, n0); n1 = fmaf(ev.y, ev.y, n1);
      n2 = fmaf(ev.z, ev.z, n2); n3 = fmaf(ev.w, ev.w, n3);
    }
    float ex = ((a0 + a1) + (a2 + a3)) - 0.5f * ((n0 + n1) + (n2 + n3));
#pragma unroll
    for (int s = 0; s < 2; ++s)
#pragma unroll
      for (int j = 0; j < 4; ++j)
        exact[s][j] = (act && sel == s * 4 + j) ? ex : exact[s][j];
    fmask = act ? (fmask & (fmask - 1)) : 0u;
  }

  // Packed (exact score, lowest-idx) reduce across the 16-lane group; combine
  // across code-split blocks via atomicMax.
#pragma unroll
  for (int s = 0; s < 2; ++s)
#pragma unroll
    for (int j = 0; j < 4; ++j) {
      unsigned long long pk = pack_score(exact[s][j], bidx[s][j]);
      unsigned long long o;
      o = __shfl_xor(pk, 1); pk = pk > o ? pk : o;
      o = __shfl_xor(pk, 2); pk = pk > o ? pk : o;
      o = __shfl_xor(pk, 4); pk = pk > o ? pk : o;
      o = __shfl_xor(pk, 8); pk = pk > o ? pk : o;
      if (cl == 0) atomicMax(&best[row0 + s * 16 + grp * 4 + j], pk);
    }
}

// Fallback (proven round-1 path) if ws is too small for the MFMA screen.
__global__ __launch_bounds__(256, 2) void vq_score_fb(
    const float* __restrict__ x, const float* __restrict__ embed,
    const float* __restrict__ enh, unsigned long long* __restrict__ best) {
  const int row = blockIdx.x * 256 + threadIdx.x;
  const int c0 = blockIdx.y * KT_FB;
  float4 xa[16];
  const float4* xg = (const float4*)(x + (size_t)row * DIM);
#pragma unroll
  for (int i = 0; i < 16; ++i) xa[i] = xg[i];
  float bs = -3.4e38f;
  int bc = 0;
#pragma unroll 2
  for (int c = c0; c < c0 + KT_FB; ++c) {
    const float4* e4 = (const float4*)(embed + (size_t)c * DIM);
    float a0 = 0.f, a1 = 0.f, a2 = 0.f, a3 = 0.f;
#pragma unroll
    for (int i = 0; i < 16; ++i) {
      float4 ev = e4[i];
      a0 = fmaf(xa[i].x, ev.x, a0); a1 = fmaf(xa[i].y, ev.y, a1);
      a2 = fmaf(xa[i].z, ev.z, a2); a3 = fmaf(xa[i].w, ev.w, a3);
    }
    float s = ((a0 + a1) + (a2 + a3)) - enh[c];
    if (s > bs) { bs = s; bc = c; }
  }
  atomicMax(&best[row], pack_score(bs, bc));
}

__global__ void vq_finalize(const unsigned long long* __restrict__ best,
                            const float* __restrict__ embed,
                            const float* __restrict__ node_mask,
                            float* __restrict__ quant,
                            float* __restrict__ out_idx,
                            float* __restrict__ counts) {
  int gid = blockIdx.x * 256 + threadIdx.x;
  int row = gid >> 6, d = gid & 63;
  unsigned long long p = best[row];
  int idx = 0xFFFF - (int)(p & 0xFFFFull);
  quant[gid] = embed[(size_t)idx * DIM + d];
  if (d == 0) {
    out_idx[row] = (float)idx;
    atomicAdd(&counts[idx], node_mask[row]);
  }
}

__global__ void vq_perplexity(const float* __restrict__ counts, float* __restrict__ out) {
  int tid = threadIdx.x;
  float acc = 0.f;
  for (int k = tid; k < NCODES; k += 256) {
    float p = counts[k] * (1.0f / (float)ROWS);
    acc += p * logf(p + 1e-10f);
  }
#pragma unroll
  for (int off = 32; off > 0; off >>= 1) acc += __shfl_down(acc, off);
  __shared__ float red[4];
  if ((tid & 63) == 0) red[tid >> 6] = acc;
  __syncthreads();
  if (tid == 0) out[0] = expf(-((red[0] + red[1]) + (red[2] + red[3])));
}

extern "C" void kernel_launch(void* const* d_in, const int* in_sizes, int n_in,
                              void* d_out, int out_size, void* d_ws, size_t ws_size,
                              hipStream_t stream) {
  const float* x = (const float*)d_in[0];
  const float* node_mask = (const float*)d_in[1];
  const float* embed = (const float*)d_in[2];

  float* out = (float*)d_out;
  float* quant = out;
  float* out_idx = out + (size_t)ROWS * DIM;
  float* out_ppl = out_idx + ROWS;

  unsigned long long* best = (unsigned long long*)((char*)d_ws + WS_BEST);
  float* counts = (float*)((char*)d_ws + WS_COUNTS);
  float* enh = (float*)((char*)d_ws + WS_ENH);
  short* eswz = (short*)((char*)d_ws + WS_ESWZ);

  hipMemsetAsync(d_ws, 0, WS_ENH, stream);  // best + counts
  vq_enorm<<<NCODES / 256, 256, 0, stream>>>(embed, enh);
  if (ws_size >= WS_NEED) {
    vq_prep_e<<<256, 256, 0, stream>>>(embed, eswz);
    vq_screen<<<dim3(ROWS / 128, NCODES / (CTS_PER_BLOCK * 16)), 256, 0, stream>>>(
        x, embed, eswz, enh, best);
  } else {
    vq_score_fb<<<dim3(ROWS / 256, NCODES / KT_FB), 256, 0, stream>>>(x, embed, enh, best);
  }
  vq_finalize<<<ROWS * DIM / 256, 256, 0, stream>>>(best, embed, node_mask, quant, out_idx, counts);
  vq_perplexity<<<1, 256, 0, stream>>>(counts, out_ppl);
}

// Round 8
// 120.704 us; speedup vs baseline: 1.9908x; 1.9908x over previous
//
#include <hip/hip_runtime.h>

typedef __attribute__((ext_vector_type(8))) short short8;
typedef __attribute__((ext_vector_type(4))) float f32x4;

#define ROWS 16384   // B*N
#define DIM 64
#define NCODES 8192
#define MARGIN 0.008f
#define BIAS 512.0f        // makes all packed scores positive -> u32 order == float order
#define PMASK 0xFFFFFFE0u  // drop 5 bits for ct_local; quantize <= ~1e-3 at |val|<1024
#define KT_FB 256
#define CTS_PER_BLOCK 32   // 512 codes per y-block
#define CHUNK 4            // cts per LDS chunk (16 KB per buffer)

// ws layout (bytes)
#define WS_BEST   0            // 16384 * 8
#define WS_COUNTS 131072       // 8192 * 4
#define WS_ENH    163840       // 8192 * 4
#define WS_ESWZ   196608       // 8192*64*2 terms * 2B = 2097152
#define WS_NEED   2293760

__device__ __forceinline__ unsigned long long pack_score(float s, int idx) {
  unsigned u = __float_as_uint(s);
  u ^= (unsigned)((int)u >> 31) | 0x80000000u;
  return ((unsigned long long)u << 32) | (unsigned)(0xFFFF - idx);
}
__device__ __forceinline__ unsigned short bf16hi(float f) {
  unsigned u = __float_as_uint(f);
  return (unsigned short)((u + 0x7FFFu + ((u >> 16) & 1u)) >> 16);
}

__global__ void vq_enorm(const float* __restrict__ embed, float* __restrict__ enh) {
  int k = blockIdx.x * 256 + threadIdx.x;
  const float4* e4 = (const float4*)(embed + (size_t)k * DIM);
  float a = 0.f, b = 0.f, c = 0.f, d = 0.f;
#pragma unroll
  for (int i = 0; i < DIM / 4; ++i) {
    float4 v = e4[i];
    a = fmaf(v.x, v.x, a); b = fmaf(v.y, v.y, b);
    c = fmaf(v.z, v.z, c); d = fmaf(v.w, v.w, d);
  }
  enh[k] = 0.5f * ((a + b) + (c + d));
}

// Pre-swizzle embed into MFMA B-fragment order, split hi/lo bf16.
// frag index = ct*4 + kc*2 + term (term 0=hi, 1=lo); element l*16B within frag.
__global__ void vq_prep_e(const float* __restrict__ embed, short* __restrict__ eswz) {
  int u = blockIdx.x * 256 + threadIdx.x;  // 65536 = 512ct * 2kc * 64l
  int l = u & 63, kc = (u >> 6) & 1, ct = u >> 7;
  int code = ct * 16 + (l & 15);
  int kb = kc * 32 + (l >> 4) * 8;
  const float* er = embed + (size_t)code * DIM + kb;
  short8 h8, l8;
#pragma unroll
  for (int j = 0; j < 8; ++j) {
    float v = er[j];
    unsigned short h = bf16hi(v);
    float r = v - __uint_as_float((unsigned)h << 16);
    h8[j] = (short)h;
    l8[j] = (short)bf16hi(r);
  }
  short8* dst = (short8*)eswz;
  size_t frag = (size_t)ct * 4 + kc * 2;
  dst[(frag + 0) * 64 + l] = h8;
  dst[(frag + 1) * 64 + l] = l8;
}

// Screen: block = 4 waves x 32 rows sharing a 512-code range. Double-buffered
// LDS staging: issue chunk ch+1's global_load_lds BEFORE computing chunk ch
// (stage latency hides under MFMA; one barrier per chunk). Scores compared as
// packed u32 (biased-positive fp32 bits | 5-bit local ct), top-2 per lane-slot
// so an in-lane approx-shadowed true winner is still rescored. Margin-gated
// exact fp32 rescore + packed u64 atomicMax (bit-exact vs numpy argmax).
__global__ __launch_bounds__(256, 4) void vq_screen(
    const float* __restrict__ x, const float* __restrict__ embed,
    const short* __restrict__ eswz, const float* __restrict__ enh,
    unsigned long long* __restrict__ best) {
  const int t = threadIdx.x;
  const int l = t & 63, wid = t >> 6;
  const int cl = l & 15, grp = l >> 4;
  const int row0 = blockIdx.x * 128 + wid * 32;
  const int ct0 = blockIdx.y * CTS_PER_BLOCK;

  __shared__ short8 bstage[2][CHUNK * 4 * 64];  // 2 x 16 KB
  __shared__ float enh_s[CTS_PER_BLOCK * 16];   // 2 KB

  const char* gbase = (const char*)eswz + (size_t)ct0 * 4 * 1024;

  // issue chunk-0 stage immediately (latency overlaps enh/A-frag setup)
  {
    char* lb = (char*)&bstage[0][0];
#pragma unroll
    for (int i = 0; i < 4; ++i) {
      const int e = i * 256 + t;
      __builtin_amdgcn_global_load_lds(
          (const __attribute__((address_space(1))) void*)(gbase + (size_t)e * 16),
          (__attribute__((address_space(3))) void*)(lb + e * 16), 16, 0, 0);
    }
  }

  enh_s[t] = enh[ct0 * 16 + t];
  enh_s[256 + t] = enh[ct0 * 16 + 256 + t];

  // A fragments: x rows -> hi/lo bf16, built in-register (one-time).
  short8 ahi[2][2], alo[2][2];
#pragma unroll
  for (int s = 0; s < 2; ++s) {
    const float4* xr4 = (const float4*)(x + (size_t)(row0 + s * 16 + cl) * DIM);
#pragma unroll
    for (int kc = 0; kc < 2; ++kc) {
      const int q = kc * 8 + grp * 2;  // float4 index of kb = kc*32+grp*8
      float4 v0 = xr4[q], v1 = xr4[q + 1];
      float vv[8] = {v0.x, v0.y, v0.z, v0.w, v1.x, v1.y, v1.z, v1.w};
#pragma unroll
      for (int j = 0; j < 8; ++j) {
        unsigned short h = bf16hi(vv[j]);
        float r = vv[j] - __uint_as_float((unsigned)h << 16);
        ahi[s][kc][j] = (short)h;
        alo[s][kc][j] = (short)bf16hi(r);
      }
    }
  }

  unsigned pb[2][4], ps[2][4];  // packed top-1 / top-2 per slot
#pragma unroll
  for (int s = 0; s < 2; ++s)
#pragma unroll
    for (int j = 0; j < 4; ++j) { pb[s][j] = 0u; ps[s][j] = 0u; }

  __syncthreads();  // chunk 0 + enh_s ready

#pragma unroll
  for (int ch = 0; ch < CTS_PER_BLOCK / CHUNK; ++ch) {
    const int cur = ch & 1;
    // prefetch next chunk into the other buffer (drained by end-of-loop barrier)
    if (ch + 1 < CTS_PER_BLOCK / CHUNK) {
      const char* gb = gbase + (size_t)(ch + 1) * CHUNK * 4 * 1024;
      char* lb = (char*)&bstage[cur ^ 1][0];
#pragma unroll
      for (int i = 0; i < 4; ++i) {
        const int e = i * 256 + t;
        __builtin_amdgcn_global_load_lds(
            (const __attribute__((address_space(1))) void*)(gb + (size_t)e * 16),
            (__attribute__((address_space(3))) void*)(lb + e * 16), 16, 0, 0);
      }
    }

    const short8* bs = &bstage[cur][0];
#pragma unroll
    for (int p = 0; p < 2; ++p) {
      const int ctlA = ch * CHUNK + 2 * p;  // compile-time local ct (5 bits)
      const int ctlB = ctlA + 1;
      const int ciA = 2 * p, ciB = 2 * p + 1;
      float ehA = enh_s[ctlA * 16 + cl];
      float ehB = enh_s[ctlB * 16 + cl];
      short8 Ah0 = bs[(ciA * 4 + 0) * 64 + l], Al0 = bs[(ciA * 4 + 1) * 64 + l];
      short8 Ah1 = bs[(ciA * 4 + 2) * 64 + l], Al1 = bs[(ciA * 4 + 3) * 64 + l];
      short8 Bh0 = bs[(ciB * 4 + 0) * 64 + l], Bl0 = bs[(ciB * 4 + 1) * 64 + l];
      short8 Bh1 = bs[(ciB * 4 + 2) * 64 + l], Bl1 = bs[(ciB * 4 + 3) * 64 + l];

      f32x4 aA0 = {BIAS - ehA, BIAS - ehA, BIAS - ehA, BIAS - ehA};
      f32x4 aB0 = {BIAS - ehB, BIAS - ehB, BIAS - ehB, BIAS - ehB};
      f32x4 aA1 = aA0, aB1 = aB0;
      // k-chunk 0, term hi*hi
      aA0 = __builtin_amdgcn_mfma_f32_16x16x32_bf16(ahi[0][0], Ah0, aA0, 0, 0, 0);
      aA1 = __builtin_amdgcn_mfma_f32_16x16x32_bf16(ahi[1][0], Ah0, aA1, 0, 0, 0);
      aB0 = __builtin_amdgcn_mfma_f32_16x16x32_bf16(ahi[0][0], Bh0, aB0, 0, 0, 0);
      aB1 = __builtin_amdgcn_mfma_f32_16x16x32_bf16(ahi[1][0], Bh0, aB1, 0, 0, 0);
      // k-chunk 0, term lo*hi
      aA0 = __builtin_amdgcn_mfma_f32_16x16x32_bf16(alo[0][0], Ah0, aA0, 0, 0, 0);
      aA1 = __builtin_amdgcn_mfma_f32_16x16x32_bf16(alo[1][0], Ah0, aA1, 0, 0, 0);
      aB0 = __builtin_amdgcn_mfma_f32_16x16x32_bf16(alo[0][0], Bh0, aB0, 0, 0, 0);
      aB1 = __builtin_amdgcn_mfma_f32_16x16x32_bf16(alo[1][0], Bh0, aB1, 0, 0, 0);
      // k-chunk 0, term hi*lo
      aA0 = __builtin_amdgcn_mfma_f32_16x16x32_bf16(ahi[0][0], Al0, aA0, 0, 0, 0);
      aA1 = __builtin_amdgcn_mfma_f32_16x16x32_bf16(ahi[1][0], Al0, aA1, 0, 0, 0);
      aB0 = __builtin_amdgcn_mfma_f32_16x16x32_bf16(ahi[0][0], Bl0, aB0, 0, 0, 0);
      aB1 = __builtin_amdgcn_mfma_f32_16x16x32_bf16(ahi[1][0], Bl0, aB1, 0, 0, 0);
      // k-chunk 1, term hi*hi
      aA0 = __builtin_amdgcn_mfma_f32_16x16x32_bf16(ahi[0][1], Ah1, aA0, 0, 0, 0);
      aA1 = __builtin_amdgcn_mfma_f32_16x16x32_bf16(ahi[1][1], Ah1, aA1, 0, 0, 0);
      aB0 = __builtin_amdgcn_mfma_f32_16x16x32_bf16(ahi[0][1], Bh1, aB0, 0, 0, 0);
      aB1 = __builtin_amdgcn_mfma_f32_16x16x32_bf16(ahi[1][1], Bh1, aB1, 0, 0, 0);
      // k-chunk 1, term lo*hi
      aA0 = __builtin_amdgcn_mfma_f32_16x16x32_bf16(alo[0][1], Ah1, aA0, 0, 0, 0);
      aA1 = __builtin_amdgcn_mfma_f32_16x16x32_bf16(alo[1][1], Ah1, aA1, 0, 0, 0);
      aB0 = __builtin_amdgcn_mfma_f32_16x16x32_bf16(alo[0][1], Bh1, aB0, 0, 0, 0);
      aB1 = __builtin_amdgcn_mfma_f32_16x16x32_bf16(alo[1][1], Bh1, aB1, 0, 0, 0);
      // k-chunk 1, term hi*lo
      aA0 = __builtin_amdgcn_mfma_f32_16x16x32_bf16(ahi[0][1], Al1, aA0, 0, 0, 0);
      aA1 = __builtin_amdgcn_mfma_f32_16x16x32_bf16(ahi[1][1], Al1, aA1, 0, 0, 0);
      aB0 = __builtin_amdgcn_mfma_f32_16x16x32_bf16(ahi[0][1], Bl1, aB0, 0, 0, 0);
      aB1 = __builtin_amdgcn_mfma_f32_16x16x32_bf16(ahi[1][1], Bl1, aB1, 0, 0, 0);

      // packed top-2 update: 4 int ops per score, no index registers
#pragma unroll
      for (int j = 0; j < 4; ++j) {
        unsigned qA0 = (__float_as_uint(aA0[j]) & PMASK) | (unsigned)ctlA;
        unsigned qA1 = (__float_as_uint(aA1[j]) & PMASK) | (unsigned)ctlA;
        unsigned qB0 = (__float_as_uint(aB0[j]) & PMASK) | (unsigned)ctlB;
        unsigned qB1 = (__float_as_uint(aB1[j]) & PMASK) | (unsigned)ctlB;
        unsigned lo;
        lo = pb[0][j] < qA0 ? pb[0][j] : qA0;
        pb[0][j] = pb[0][j] > qA0 ? pb[0][j] : qA0;
        ps[0][j] = ps[0][j] > lo ? ps[0][j] : lo;
        lo = pb[0][j] < qB0 ? pb[0][j] : qB0;
        pb[0][j] = pb[0][j] > qB0 ? pb[0][j] : qB0;
        ps[0][j] = ps[0][j] > lo ? ps[0][j] : lo;
        lo = pb[1][j] < qA1 ? pb[1][j] : qA1;
        pb[1][j] = pb[1][j] > qA1 ? pb[1][j] : qA1;
        ps[1][j] = ps[1][j] > lo ? ps[1][j] : lo;
        lo = pb[1][j] < qB1 ? pb[1][j] : qB1;
        pb[1][j] = pb[1][j] > qB1 ? pb[1][j] : qB1;
        ps[1][j] = ps[1][j] > lo ? ps[1][j] : lo;
      }
    }
    __syncthreads();  // waves done reading bstage[cur]; next chunk's loads drained
  }

  // Row max over 16 lanes per slot; flag top-1/top-2 within margin of row max.
  unsigned fmask = 0;  // bits 0..7: pb flags, bits 8..15: ps flags
#pragma unroll
  for (int s = 0; s < 2; ++s)
#pragma unroll
    for (int j = 0; j < 4; ++j) {
      unsigned m = pb[s][j], o;
      o = __shfl_xor(m, 1); m = m > o ? m : o;
      o = __shfl_xor(m, 2); m = m > o ? m : o;
      o = __shfl_xor(m, 4); m = m > o ? m : o;
      o = __shfl_xor(m, 8); m = m > o ? m : o;
      float mf = __uint_as_float(m & PMASK) - MARGIN;
      if (__uint_as_float(pb[s][j] & PMASK) >= mf) fmask |= 1u << (s * 4 + j);
      if (__uint_as_float(ps[s][j] & PMASK) >= mf) fmask |= 1u << (s * 4 + j + 8);
    }

  // Exact fp32 rescore of flagged candidates, packed u64 per slot.
  unsigned long long exactp[2][4];
#pragma unroll
  for (int s = 0; s < 2; ++s)
#pragma unroll
    for (int j = 0; j < 4; ++j) exactp[s][j] = 0ull;

  while (__any((int)(fmask != 0))) {
    const bool act = fmask != 0;
    const int sel = act ? __ffs(fmask) - 1 : 0;
    const int slot = sel & 7, which = sel >> 3;
    unsigned pk = 0;
#pragma unroll
    for (int s = 0; s < 2; ++s)
#pragma unroll
      for (int j = 0; j < 4; ++j)
        if (slot == s * 4 + j) pk = which ? ps[s][j] : pb[s][j];
    const int code = act ? (ct0 + (int)(pk & 31u)) * 16 + cl : 0;
    const int row = act ? row0 + (slot >> 2) * 16 + grp * 4 + (slot & 3) : row0;
    const float4* xr = (const float4*)(x + (size_t)row * DIM);
    const float4* er = (const float4*)(embed + (size_t)code * DIM);
    float a0 = 0, a1 = 0, a2 = 0, a3 = 0, n0 = 0, n1 = 0, n2 = 0, n3 = 0;
#pragma unroll
    for (int i = 0; i < 16; ++i) {
      float4 xv = xr[i], ev = er[i];
      a0 = fmaf(xv.x, ev.x, a0); a1 = fmaf(xv.y, ev.y, a1);
      a2 = fmaf(xv.z, ev.z, a2); a3 = fmaf(xv.w, ev.w, a3);
      n0 = fmaf(ev.x, ev.x, n0); n1 = fmaf(ev.y, ev.y, n1);
      n2 = fmaf(ev.z, ev.z, n2); n3 = fmaf(ev.w, ev.w, n3);
    }
    float ex = ((a0 + a1) + (a2 + a3)) - 0.5f * ((n0 + n1) + (n2 + n3));
    unsigned long long cand = act ? pack_score(ex, code) : 0ull;
#pragma unroll
    for (int s = 0; s < 2; ++s)
#pragma unroll
      for (int j = 0; j < 4; ++j)
        if (slot == s * 4 + j) exactp[s][j] = exactp[s][j] > cand ? exactp[s][j] : cand;
    fmask = act ? (fmask & (fmask - 1)) : 0u;
  }

  // (exact score, lowest-idx) reduce across the 16-lane group; atomicMax combine.
#pragma unroll
  for (int s = 0; s < 2; ++s)
#pragma unroll
    for (int j = 0; j < 4; ++j) {
      unsigned long long pk = exactp[s][j], o;
      o = __shfl_xor(pk, 1); pk = pk > o ? pk : o;
      o = __shfl_xor(pk, 2); pk = pk > o ? pk : o;
      o = __shfl_xor(pk, 4); pk = pk > o ? pk : o;
      o = __shfl_xor(pk, 8); pk = pk > o ? pk : o;
      if (cl == 0) atomicMax(&best[row0 + s * 16 + grp * 4 + j], pk);
    }
}

// Fallback (proven round-1 path) if ws is too small for the MFMA screen.
__global__ __launch_bounds__(256, 2) void vq_score_fb(
    const float* __restrict__ x, const float* __restrict__ embed,
    const float* __restrict__ enh, unsigned long long* __restrict__ best) {
  const int row = blockIdx.x * 256 + threadIdx.x;
  const int c0 = blockIdx.y * KT_FB;
  float4 xa[16];
  const float4* xg = (const float4*)(x + (size_t)row * DIM);
#pragma unroll
  for (int i = 0; i < 16; ++i) xa[i] = xg[i];
  float bs = -3.4e38f;
  int bc = 0;
#pragma unroll 2
  for (int c = c0; c < c0 + KT_FB; ++c) {
    const float4* e4 = (const float4*)(embed + (size_t)c * DIM);
    float a0 = 0.f, a1 = 0.f, a2 = 0.f, a3 = 0.f;
#pragma unroll
    for (int i = 0; i < 16; ++i) {
      float4 ev = e4[i];
      a0 = fmaf(xa[i].x, ev.x, a0); a1 = fmaf(xa[i].y, ev.y, a1);
      a2 = fmaf(xa[i].z, ev.z, a2); a3 = fmaf(xa[i].w, ev.w, a3);
    }
    float s = ((a0 + a1) + (a2 + a3)) - enh[c];
    if (s > bs) { bs = s; bc = c; }
  }
  atomicMax(&best[row], pack_score(bs, bc));
}

__global__ void vq_finalize(const unsigned long long* __restrict__ best,
                            const float* __restrict__ embed,
                            const float* __restrict__ node_mask,
                            float* __restrict__ quant,
                            float* __restrict__ out_idx,
                            float* __restrict__ counts) {
  int gid = blockIdx.x * 256 + threadIdx.x;
  int row = gid >> 6, d = gid & 63;
  unsigned long long p = best[row];
  int idx = 0xFFFF - (int)(p & 0xFFFFull);
  quant[gid] = embed[(size_t)idx * DIM + d];
  if (d == 0) {
    out_idx[row] = (float)idx;
    atomicAdd(&counts[idx], node_mask[row]);
  }
}

__global__ void vq_perplexity(const float* __restrict__ counts, float* __restrict__ out) {
  int tid = threadIdx.x;
  float acc = 0.f;
  for (int k = tid; k < NCODES; k += 256) {
    float p = counts[k] * (1.0f / (float)ROWS);
    acc += p * logf(p + 1e-10f);
  }
#pragma unroll
  for (int off = 32; off > 0; off >>= 1) acc += __shfl_down(acc, off);
  __shared__ float red[4];
  if ((tid & 63) == 0) red[tid >> 6] = acc;
  __syncthreads();
  if (tid == 0) out[0] = expf(-((red[0] + red[1]) + (red[2] + red[3])));
}

extern "C" void kernel_launch(void* const* d_in, const int* in_sizes, int n_in,
                              void* d_out, int out_size, void* d_ws, size_t ws_size,
                              hipStream_t stream) {
  const float* x = (const float*)d_in[0];
  const float* node_mask = (const float*)d_in[1];
  const float* embed = (const float*)d_in[2];

  float* out = (float*)d_out;
  float* quant = out;
  float* out_idx = out + (size_t)ROWS * DIM;
  float* out_ppl = out_idx + ROWS;

  unsigned long long* best = (unsigned long long*)((char*)d_ws + WS_BEST);
  float* counts = (float*)((char*)d_ws + WS_COUNTS);
  float* enh = (float*)((char*)d_ws + WS_ENH);
  short* eswz = (short*)((char*)d_ws + WS_ESWZ);

  hipMemsetAsync(d_ws, 0, WS_ENH, stream);  // best + counts
  vq_enorm<<<NCODES / 256, 256, 0, stream>>>(embed, enh);
  if (ws_size >= WS_NEED) {
    vq_prep_e<<<256, 256, 0, stream>>>(embed, eswz);
    vq_screen<<<dim3(ROWS / 128, NCODES / (CTS_PER_BLOCK * 16)), 256, 0, stream>>>(
        x, embed, eswz, enh, best);
  } else {
    vq_score_fb<<<dim3(ROWS / 256, NCODES / KT_FB), 256, 0, stream>>>(x, embed, enh, best);
  }
  vq_finalize<<<ROWS * DIM / 256, 256, 0, stream>>>(best, embed, node_mask, quant, out_idx, counts);
  vq_perplexity<<<1, 256, 0, stream>>>(counts, out_ppl);
}

// Round 9
// 107.997 us; speedup vs baseline: 2.2250x; 1.1177x over previous
//
#include <hip/hip_runtime.h>

typedef __attribute__((ext_vector_type(8))) short short8;
typedef __attribute__((ext_vector_type(4))) float f32x4;

#define ROWS 16384   // B*N
#define DIM 64
#define NCODES 8192
#define MARGIN 0.008f
#define KT_FB 256
#define CTS_PER_BLOCK 32   // 512 codes per y-block
#define CHUNK 4            // cts per LDS buffer (16 KB)

// ws layout (bytes)
#define WS_BEST   0            // 16384 * 8
#define WS_COUNTS 131072       // 8192 * 4
#define WS_ENH    163840       // 8192 * 4
#define WS_ESWZ   196608       // 8192*64*2 terms * 2B = 2097152
#define WS_NEED   2293760

__device__ __forceinline__ unsigned long long pack_score(float s, int idx) {
  unsigned u = __float_as_uint(s);
  u ^= (unsigned)((int)u >> 31) | 0x80000000u;
  return ((unsigned long long)u << 32) | (unsigned)(0xFFFF - idx);
}
__device__ __forceinline__ unsigned short bf16hi(float f) {
  unsigned u = __float_as_uint(f);
  return (unsigned short)((u + 0x7FFFu + ((u >> 16) & 1u)) >> 16);
}

__global__ void vq_enorm(const float* __restrict__ embed, float* __restrict__ enh) {
  int k = blockIdx.x * 256 + threadIdx.x;
  const float4* e4 = (const float4*)(embed + (size_t)k * DIM);
  float a = 0.f, b = 0.f, c = 0.f, d = 0.f;
#pragma unroll
  for (int i = 0; i < DIM / 4; ++i) {
    float4 v = e4[i];
    a = fmaf(v.x, v.x, a); b = fmaf(v.y, v.y, b);
    c = fmaf(v.z, v.z, c); d = fmaf(v.w, v.w, d);
  }
  enh[k] = 0.5f * ((a + b) + (c + d));
}

// Pre-swizzle embed into MFMA B-fragment order, split hi/lo bf16.
// frag index = ct*4 + kc*2 + term (term 0=hi, 1=lo); element l*16B within frag.
__global__ void vq_prep_e(const float* __restrict__ embed, short* __restrict__ eswz) {
  int u = blockIdx.x * 256 + threadIdx.x;  // 65536 = 512ct * 2kc * 64l
  int l = u & 63, kc = (u >> 6) & 1, ct = u >> 7;
  int code = ct * 16 + (l & 15);
  int kb = kc * 32 + (l >> 4) * 8;
  const float* er = embed + (size_t)code * DIM + kb;
  short8 h8, l8;
#pragma unroll
  for (int j = 0; j < 8; ++j) {
    float v = er[j];
    unsigned short h = bf16hi(v);
    float r = v - __uint_as_float((unsigned)h << 16);
    h8[j] = (short)h;
    l8[j] = (short)bf16hi(r);
  }
  short8* dst = (short8*)eswz;
  size_t frag = (size_t)ct * 4 + kc * 2;
  dst[(frag + 0) * 64 + l] = h8;
  dst[(frag + 1) * 64 + l] = l8;
}

// Screen: block = 4 waves x 32 rows sharing a 512-code range. Double-buffered
// LDS staging (prefetch chunk ch+1 before computing ch; one barrier/chunk).
// Per ct: k-split accumulators -> 4 independent 3-deep MFMA chains (r6 was
// 2 chains x 6-deep; the 60% stall was chain-dependency latency). -||e||^2/2
// folded into the k0 chain init; merge = one f32x4 add at compare time.
// Float top-1 compare per lane-slot (r6-proven, no spill), margin-gated exact
// fp32 rescore, packed u64 atomicMax (bit-exact vs numpy argmax).
__global__ __launch_bounds__(256, 4) void vq_screen(
    const float* __restrict__ x, const float* __restrict__ embed,
    const short* __restrict__ eswz, const float* __restrict__ enh,
    unsigned long long* __restrict__ best) {
  const int t = threadIdx.x;
  const int l = t & 63, wid = t >> 6;
  const int cl = l & 15, grp = l >> 4;
  const int row0 = blockIdx.x * 128 + wid * 32;
  const int ct0 = blockIdx.y * CTS_PER_BLOCK;

  __shared__ short8 bstage[2][CHUNK * 4 * 64];  // 2 x 16 KB
  __shared__ float enh_s[CTS_PER_BLOCK * 16];   // 2 KB

  const char* gbase = (const char*)eswz + (size_t)ct0 * 4 * 1024;

  // issue chunk-0 stage immediately (latency overlaps enh/A-frag setup)
  {
    char* lb = (char*)&bstage[0][0];
#pragma unroll
    for (int i = 0; i < 4; ++i) {
      const int e = i * 256 + t;
      __builtin_amdgcn_global_load_lds(
          (const __attribute__((address_space(1))) void*)(gbase + (size_t)e * 16),
          (__attribute__((address_space(3))) void*)(lb + e * 16), 16, 0, 0);
    }
  }

  enh_s[t] = enh[ct0 * 16 + t];
  enh_s[256 + t] = enh[ct0 * 16 + 256 + t];

  // A fragments: x rows -> hi/lo bf16, built in-register (one-time).
  short8 ahi[2][2], alo[2][2];
#pragma unroll
  for (int s = 0; s < 2; ++s) {
    const float4* xr4 = (const float4*)(x + (size_t)(row0 + s * 16 + cl) * DIM);
#pragma unroll
    for (int kc = 0; kc < 2; ++kc) {
      const int q = kc * 8 + grp * 2;  // float4 index of kb = kc*32+grp*8
      float4 v0 = xr4[q], v1 = xr4[q + 1];
      float vv[8] = {v0.x, v0.y, v0.z, v0.w, v1.x, v1.y, v1.z, v1.w};
#pragma unroll
      for (int j = 0; j < 8; ++j) {
        unsigned short h = bf16hi(vv[j]);
        float r = vv[j] - __uint_as_float((unsigned)h << 16);
        ahi[s][kc][j] = (short)h;
        alo[s][kc][j] = (short)bf16hi(r);
      }
    }
  }

  float bsc[2][4];
  int bidx[2][4];
#pragma unroll
  for (int s = 0; s < 2; ++s)
#pragma unroll
    for (int j = 0; j < 4; ++j) { bsc[s][j] = -3.4e38f; bidx[s][j] = 0; }

  __syncthreads();  // chunk 0 + enh_s ready

#pragma unroll
  for (int ch = 0; ch < CTS_PER_BLOCK / CHUNK; ++ch) {
    const int cur = ch & 1;
    // prefetch next chunk into the other buffer (drained at end-of-chunk barrier)
    if (ch + 1 < CTS_PER_BLOCK / CHUNK) {
      const char* gb = gbase + (size_t)(ch + 1) * CHUNK * 4 * 1024;
      char* lb = (char*)&bstage[cur ^ 1][0];
#pragma unroll
      for (int i = 0; i < 4; ++i) {
        const int e = i * 256 + t;
        __builtin_amdgcn_global_load_lds(
            (const __attribute__((address_space(1))) void*)(gb + (size_t)e * 16),
            (__attribute__((address_space(3))) void*)(lb + e * 16), 16, 0, 0);
      }
    }

    const short8* bs = &bstage[cur][0];
#pragma unroll
    for (int ci = 0; ci < CHUNK; ++ci) {
      const int ctl = ch * CHUNK + ci;  // local ct, compile-time constant
      const float eh = enh_s[ctl * 16 + cl];
      short8 h0 = bs[(ci * 4 + 0) * 64 + l], l0 = bs[(ci * 4 + 1) * 64 + l];
      short8 h1 = bs[(ci * 4 + 2) * 64 + l], l1 = bs[(ci * 4 + 3) * 64 + l];

      f32x4 a00 = {-eh, -eh, -eh, -eh};  // slot0, k-chunk0 (carries the bias)
      f32x4 a10 = a00;                   // slot1, k-chunk0
      f32x4 a01 = {0.f, 0.f, 0.f, 0.f};  // slot0, k-chunk1
      f32x4 a11 = a01;                   // slot1, k-chunk1
      // 4 independent chains, 3 MFMAs deep, interleaved round-robin
      a00 = __builtin_amdgcn_mfma_f32_16x16x32_bf16(ahi[0][0], h0, a00, 0, 0, 0);
      a10 = __builtin_amdgcn_mfma_f32_16x16x32_bf16(ahi[1][0], h0, a10, 0, 0, 0);
      a01 = __builtin_amdgcn_mfma_f32_16x16x32_bf16(ahi[0][1], h1, a01, 0, 0, 0);
      a11 = __builtin_amdgcn_mfma_f32_16x16x32_bf16(ahi[1][1], h1, a11, 0, 0, 0);
      a00 = __builtin_amdgcn_mfma_f32_16x16x32_bf16(alo[0][0], h0, a00, 0, 0, 0);
      a10 = __builtin_amdgcn_mfma_f32_16x16x32_bf16(alo[1][0], h0, a10, 0, 0, 0);
      a01 = __builtin_amdgcn_mfma_f32_16x16x32_bf16(alo[0][1], h1, a01, 0, 0, 0);
      a11 = __builtin_amdgcn_mfma_f32_16x16x32_bf16(alo[1][1], h1, a11, 0, 0, 0);
      a00 = __builtin_amdgcn_mfma_f32_16x16x32_bf16(ahi[0][0], l0, a00, 0, 0, 0);
      a10 = __builtin_amdgcn_mfma_f32_16x16x32_bf16(ahi[1][0], l0, a10, 0, 0, 0);
      a01 = __builtin_amdgcn_mfma_f32_16x16x32_bf16(ahi[0][1], l1, a01, 0, 0, 0);
      a11 = __builtin_amdgcn_mfma_f32_16x16x32_bf16(ahi[1][1], l1, a11, 0, 0, 0);

      f32x4 s0 = a00 + a01;  // merge k-chunks
      f32x4 s1 = a10 + a11;
      const int code = (ct0 + ctl) * 16 + cl;
#pragma unroll
      for (int j = 0; j < 4; ++j) {
        if (s0[j] > bsc[0][j]) { bsc[0][j] = s0[j]; bidx[0][j] = code; }
        if (s1[j] > bsc[1][j]) { bsc[1][j] = s1[j]; bidx[1][j] = code; }
      }
    }
    __syncthreads();  // done reading bstage[cur]; prefetch drained
  }

  // Row max over the 16 lanes (l&15) of each group; flag lane-bests within margin.
  unsigned fmask = 0;
#pragma unroll
  for (int s = 0; s < 2; ++s)
#pragma unroll
    for (int j = 0; j < 4; ++j) {
      float m = bsc[s][j];
      m = fmaxf(m, __shfl_xor(m, 1));
      m = fmaxf(m, __shfl_xor(m, 2));
      m = fmaxf(m, __shfl_xor(m, 4));
      m = fmaxf(m, __shfl_xor(m, 8));
      if (bsc[s][j] >= m - MARGIN) fmask |= 1u << (s * 4 + j);
    }

  // Exact fp32 rescore of flagged candidates (typically 1/lane), lane-compacted.
  float exact[2][4];
#pragma unroll
  for (int s = 0; s < 2; ++s)
#pragma unroll
    for (int j = 0; j < 4; ++j) exact[s][j] = -3.4e38f;

  while (__any((int)(fmask != 0))) {
    const bool act = fmask != 0;
    const int sel = act ? __ffs(fmask) - 1 : 0;
    int code = 0;
#pragma unroll
    for (int s = 0; s < 2; ++s)
#pragma unroll
      for (int j = 0; j < 4; ++j)
        code = (sel == s * 4 + j) ? bidx[s][j] : code;
    int row = act ? (row0 + (sel >> 2) * 16 + grp * 4 + (sel & 3)) : row0;
    if (!act) code = 0;
    const float4* xr = (const float4*)(x + (size_t)row * DIM);
    const float4* er = (const float4*)(embed + (size_t)code * DIM);
    float a0 = 0, a1 = 0, a2 = 0, a3 = 0, n0 = 0, n1 = 0, n2 = 0, n3 = 0;
#pragma unroll
    for (int i = 0; i < 16; ++i) {
      float4 xv = xr[i], ev = er[i];
      a0 = fmaf(xv.x, ev.x, a0); a1 = fmaf(xv.y, ev.y, a1);
      a2 = fmaf(xv.z, ev.z, a2); a3 = fmaf(xv.w, ev.w, a3);
      n0 = fmaf(ev.x, ev.x, n0); n1 = fmaf(ev.y, ev.y, n1);
      n2 = fmaf(ev.z, ev.z, n2); n3 = fmaf(ev.w, ev.w, n3);
    }
    float ex = ((a0 + a1) + (a2 + a3)) - 0.5f * ((n0 + n1) + (n2 + n3));
#pragma unroll
    for (int s = 0; s < 2; ++s)
#pragma unroll
      for (int j = 0; j < 4; ++j)
        exact[s][j] = (act && sel == s * 4 + j) ? ex : exact[s][j];
    fmask = act ? (fmask & (fmask - 1)) : 0u;
  }

  // (exact score, lowest-idx) reduce across the 16-lane group; atomicMax combine.
#pragma unroll
  for (int s = 0; s < 2; ++s)
#pragma unroll
    for (int j = 0; j < 4; ++j) {
      unsigned long long pk = pack_score(exact[s][j], bidx[s][j]);
      unsigned long long o;
      o = __shfl_xor(pk, 1); pk = pk > o ? pk : o;
      o = __shfl_xor(pk, 2); pk = pk > o ? pk : o;
      o = __shfl_xor(pk, 4); pk = pk > o ? pk : o;
      o = __shfl_xor(pk, 8); pk = pk > o ? pk : o;
      if (cl == 0) atomicMax(&best[row0 + s * 16 + grp * 4 + j], pk);
    }
}

// Fallback (proven round-1 path) if ws is too small for the MFMA screen.
__global__ __launch_bounds__(256, 2) void vq_score_fb(
    const float* __restrict__ x, const float* __restrict__ embed,
    const float* __restrict__ enh, unsigned long long* __restrict__ best) {
  const int row = blockIdx.x * 256 + threadIdx.x;
  const int c0 = blockIdx.y * KT_FB;
  float4 xa[16];
  const float4* xg = (const float4*)(x + (size_t)row * DIM);
#pragma unroll
  for (int i = 0; i < 16; ++i) xa[i] = xg[i];
  float bs = -3.4e38f;
  int bc = 0;
#pragma unroll 2
  for (int c = c0; c < c0 + KT_FB; ++c) {
    const float4* e4 = (const float4*)(embed + (size_t)c * DIM);
    float a0 = 0.f, a1 = 0.f, a2 = 0.f, a3 = 0.f;
#pragma unroll
    for (int i = 0; i < 16; ++i) {
      float4 ev = e4[i];
      a0 = fmaf(xa[i].x, ev.x, a0); a1 = fmaf(xa[i].y, ev.y, a1);
      a2 = fmaf(xa[i].z, ev.z, a2); a3 = fmaf(xa[i].w, ev.w, a3);
    }
    float s = ((a0 + a1) + (a2 + a3)) - enh[c];
    if (s > bs) { bs = s; bc = c; }
  }
  atomicMax(&best[row], pack_score(bs, bc));
}

__global__ void vq_finalize(const unsigned long long* __restrict__ best,
                            const float* __restrict__ embed,
                            const float* __restrict__ node_mask,
                            float* __restrict__ quant,
                            float* __restrict__ out_idx,
                            float* __restrict__ counts) {
  int gid = blockIdx.x * 256 + threadIdx.x;
  int row = gid >> 6, d = gid & 63;
  unsigned long long p = best[row];
  int idx = 0xFFFF - (int)(p & 0xFFFFull);
  quant[gid] = embed[(size_t)idx * DIM + d];
  if (d == 0) {
    out_idx[row] = (float)idx;
    atomicAdd(&counts[idx], node_mask[row]);
  }
}

__global__ void vq_perplexity(const float* __restrict__ counts, float* __restrict__ out) {
  int tid = threadIdx.x;
  float acc = 0.f;
  for (int k = tid; k < NCODES; k += 256) {
    float p = counts[k] * (1.0f / (float)ROWS);
    acc += p * logf(p + 1e-10f);
  }
#pragma unroll
  for (int off = 32; off > 0; off >>= 1) acc += __shfl_down(acc, off);
  __shared__ float red[4];
  if ((tid & 63) == 0) red[tid >> 6] = acc;
  __syncthreads();
  if (tid == 0) out[0] = expf(-((red[0] + red[1]) + (red[2] + red[3])));
}

extern "C" void kernel_launch(void* const* d_in, const int* in_sizes, int n_in,
                              void* d_out, int out_size, void* d_ws, size_t ws_size,
                              hipStream_t stream) {
  const float* x = (const float*)d_in[0];
  const float* node_mask = (const float*)d_in[1];
  const float* embed = (const float*)d_in[2];

  float* out = (float*)d_out;
  float* quant = out;
  float* out_idx = out + (size_t)ROWS * DIM;
  float* out_ppl = out_idx + ROWS;

  unsigned long long* best = (unsigned long long*)((char*)d_ws + WS_BEST);
  float* counts = (float*)((char*)d_ws + WS_COUNTS);
  float* enh = (float*)((char*)d_ws + WS_ENH);
  short* eswz = (short*)((char*)d_ws + WS_ESWZ);

  hipMemsetAsync(d_ws, 0, WS_ENH, stream);  // best + counts
  vq_enorm<<<NCODES / 256, 256, 0, stream>>>(embed, enh);
  if (ws_size >= WS_NEED) {
    vq_prep_e<<<256, 256, 0, stream>>>(embed, eswz);
    vq_screen<<<dim3(ROWS / 128, NCODES / (CTS_PER_BLOCK * 16)), 256, 0, stream>>>(
        x, embed, eswz, enh, best);
  } else {
    vq_score_fb<<<dim3(ROWS / 256, NCODES / KT_FB), 256, 0, stream>>>(x, embed, enh, best);
  }
  vq_finalize<<<ROWS * DIM / 256, 256, 0, stream>>>(best, embed, node_mask, quant, out_idx, counts);
  vq_perplexity<<<1, 256, 0, stream>>>(counts, out_ppl);
}